// Round 7
// baseline (296.799 us; speedup 1.0000x reference)
//
#include <hip/hip_runtime.h>

#define BM 128
#define BN 128
#define BK 32

typedef __attribute__((ext_vector_type(8))) _Float16 half8;   // MFMA A/B frag
typedef __attribute__((ext_vector_type(2))) __fp16 h2raw;     // cvt_pkrtz result
typedef __attribute__((ext_vector_type(16))) float floatx16;  // 32x32 MFMA C/D
typedef __attribute__((ext_vector_type(4))) float f4;         // raw float4

#define AS1U(p) ((const __attribute__((address_space(1))) unsigned int*)(p))
#define AS3U(p) ((__attribute__((address_space(3))) unsigned int*)(p))

union H8 {
    h2raw h2[4];
    half8 h8;
};

__device__ inline half8 cvt8(f4 a, f4 b) {
    H8 u;
    u.h2[0] = __builtin_amdgcn_cvt_pkrtz(a.x, a.y);
    u.h2[1] = __builtin_amdgcn_cvt_pkrtz(a.z, a.w);
    u.h2[2] = __builtin_amdgcn_cvt_pkrtz(b.x, b.y);
    u.h2[3] = __builtin_amdgcn_cvt_pkrtz(b.z, b.w);
    return u.h8;
}

// Fused kernel: fp32 x,W staged direct-to-LDS; in-register fp16 cvt;
// 32x32x16 f16 MFMA; DIRECT coalesced epilogue (C/D layout col=lane&31 ->
// each per-reg scalar access is 2x128B cache lines; no LDS transpose).
__global__ __launch_bounds__(256, 4) void gumbel_fused(
        const float* __restrict__ x, const float* __restrict__ W,
        const float* __restrict__ bias, const float* __restrict__ u1,
        const float* __restrict__ u2, float* __restrict__ out,
        int M, int N, int K) {
    __shared__ float Smem[8192];   // A fp32 tile (4096 f) + B fp32 tile (4096 f)
    float* As = Smem;
    float* Bs = Smem + 4096;

    const int tid  = threadIdx.x;
    const int lane = tid & 63;
    const int wave = tid >> 6;

    // bid%8 == by%8 for all 8 sharers of an x row-panel -> same XCD L2.
    const int bid = blockIdx.x;
    const int by  = bid & (M / BM - 1);   // M/BM = 128 (pow2)
    const int bx  = bid >> 7;
    const int bm = by * BM;
    const int bn = bx * BN;

    // --- staging: tile = 1024 16B chunks (8 chunks/row of 32 floats).
    // LDS chunk s <- global (row r = s>>3, chunk col cc = (s&7) ^ (r&7)).
    // Swizzle on the GLOBAL side; LDS side stays lane-ordered
    // (global_load_lds: lds addr = wave-uniform base + lane*16).
    int aoff[4], boff[4], lsoff[4];
#pragma unroll
    for (int rep = 0; rep < 4; rep++) {
        int s = wave * 64 + lane + rep * 256;
        int r = s >> 3;
        int cc = (s & 7) ^ (r & 7);
        aoff[rep] = (bm + r) * K + cc * 4;
        boff[rep] = (bn + r) * K + cc * 4;
        lsoff[rep] = s * 4;
    }

    // --- fragment addressing (32x32x16: A[m=lane&31][k=(lane>>5)*8+j]) ---
    const int l31  = lane & 31;
    const int half = lane >> 5;
    const int wm = (wave & 1) * 64;   // 2x2 wave grid, wave tile 64x64
    const int wn = (wave >> 1) * 64;

    floatx16 acc[2][2] = {};

    // LDS position of global k-chunk c for row r is c^(r&7); the 8-float
    // fragment spans chunks c0,c0+1 with c0 even -> partner pos = p0^1.
    int aro[2][2], bro[2][2];   // [m/n tile][k-step] float offsets
#pragma unroll
    for (int mi = 0; mi < 2; mi++) {
        int ra = wm + mi * 32 + l31;
        int rb = wn + mi * 32 + l31;
#pragma unroll
        for (int s = 0; s < 2; s++) {
            int c0 = s * 4 + half * 2;
            aro[mi][s] = ra * 32 + (c0 ^ (ra & 7)) * 4;
            bro[mi][s] = rb * 32 + (c0 ^ (rb & 7)) * 4;
        }
    }

    for (int kb = 0; kb < K; kb += BK) {
#pragma unroll
        for (int rep = 0; rep < 4; rep++) {
            __builtin_amdgcn_global_load_lds(AS1U(x + aoff[rep] + kb), AS3U(As + lsoff[rep]), 16, 0, 0);
            __builtin_amdgcn_global_load_lds(AS1U(W + boff[rep] + kb), AS3U(Bs + lsoff[rep]), 16, 0, 0);
        }
        __syncthreads();

        half8 af[2][2], bf[2][2];
#pragma unroll
        for (int mi = 0; mi < 2; mi++) {
#pragma unroll
            for (int s = 0; s < 2; s++) {
                f4 a0 = *(const f4*)(As + aro[mi][s]);
                f4 a1 = *(const f4*)(As + ((aro[mi][s] & ~31) | ((aro[mi][s] & 31) ^ 4)));
                af[mi][s] = cvt8(a0, a1);   // a0 = even k-chunk, a1 = odd, always
                f4 b0 = *(const f4*)(Bs + bro[mi][s]);
                f4 b1 = *(const f4*)(Bs + ((bro[mi][s] & ~31) | ((bro[mi][s] & 31) ^ 4)));
                bf[mi][s] = cvt8(b0, b1);
            }
        }
#pragma unroll
        for (int mi = 0; mi < 2; mi++) {
#pragma unroll
            for (int ni = 0; ni < 2; ni++) {
                acc[mi][ni] = __builtin_amdgcn_mfma_f32_32x32x16_f16(af[mi][0], bf[ni][0], acc[mi][ni], 0, 0, 0);
                acc[mi][ni] = __builtin_amdgcn_mfma_f32_32x32x16_f16(af[mi][1], bf[ni][1], acc[mi][ni], 0, 0, 0);
            }
        }
        __syncthreads();
    }

    // --- epilogue: direct, fully coalesced (per reg: 64 lanes = 2 rows x 128B) ---
    // C/D: col = lane&31, row = (reg&3) + 8*(reg>>2) + 4*(lane>>5)
    const float inv_t = 10.0f;  // 1/TEMP
    float bv[2];
#pragma unroll
    for (int ni = 0; ni < 2; ni++) bv[ni] = bias[bn + wn + ni * 32 + l31];

#pragma unroll
    for (int mi = 0; mi < 2; mi++) {
#pragma unroll
        for (int ni = 0; ni < 2; ni++) {
            int colg = bn + wn + ni * 32 + l31;
            int row0 = bm + wm + mi * 32 + 4 * half;
#pragma unroll
            for (int reg = 0; reg < 16; reg++) {
                int row = row0 + (reg & 3) + 8 * (reg >> 2);
                int idx = row * N + colg;
                float v1 = __builtin_nontemporal_load(&u1[idx]);
                float v2 = __builtin_nontemporal_load(&u2[idx]);
                float l = acc[mi][ni][reg] + bv[ni];
                float z = (l + __logf(__logf(v2) / __logf(v1))) * inv_t;
                float o = 1.0f / (1.0f + __expf(-z));
                __builtin_nontemporal_store(o, &out[idx]);
            }
        }
    }
}

extern "C" void kernel_launch(void* const* d_in, const int* in_sizes, int n_in,
                              void* d_out, int out_size, void* d_ws, size_t ws_size,
                              hipStream_t stream) {
    const float* x  = (const float*)d_in[0];
    const float* u1 = (const float*)d_in[1];
    const float* u2 = (const float*)d_in[2];
    const float* W  = (const float*)d_in[3];
    const float* b  = (const float*)d_in[4];
    float* out = (float*)d_out;

    const int N = in_sizes[4];            // 1024
    const int K = in_sizes[3] / N;        // 1024
    const int M = in_sizes[0] / K;        // 16384

    dim3 grid((M / BM) * (N / BN));       // 128 * 8 = 1024
    gumbel_fused<<<grid, 256, 0, stream>>>(x, W, b, u1, u2, out, M, N, K);
}

// Round 8
// 251.435 us; speedup vs baseline: 1.1804x; 1.1804x over previous
//
#include <hip/hip_runtime.h>

#define BM 128
#define BN 128
#define BK 64

typedef __attribute__((ext_vector_type(8))) _Float16 half8;   // MFMA A/B frag
typedef __attribute__((ext_vector_type(2))) __fp16 h2raw;     // cvt_pkrtz result
typedef __attribute__((ext_vector_type(4))) float floatx4;    // MFMA C/D frag
typedef __attribute__((ext_vector_type(4))) float f4;         // raw float4

#define AS1U(p) ((const __attribute__((address_space(1))) unsigned int*)(p))
#define AS3U(p) ((__attribute__((address_space(3))) unsigned int*)(p))

// ---------- prepass: fp32 -> fp16 for x AND W in one dispatch ----------
__global__ __launch_bounds__(256) void cvt_fp32_fp16_2(
        const float* __restrict__ x, _Float16* __restrict__ xh, int nx8,
        const float* __restrict__ W, _Float16* __restrict__ wh, int nw8,
        int xblocks) {
    const f4* s4;
    half8* d8;
    int n8, i, stride;
    if ((int)blockIdx.x < xblocks) {
        s4 = (const f4*)x; d8 = (half8*)xh; n8 = nx8;
        i = blockIdx.x * blockDim.x + threadIdx.x;
        stride = xblocks * blockDim.x;
    } else {
        s4 = (const f4*)W; d8 = (half8*)wh; n8 = nw8;
        i = (blockIdx.x - xblocks) * blockDim.x + threadIdx.x;
        stride = (gridDim.x - xblocks) * blockDim.x;
    }
    union { h2raw h2[4]; half8 h8; } u;
    for (; i < n8; i += stride) {
        f4 a = s4[2 * i];
        f4 b = s4[2 * i + 1];
        u.h2[0] = __builtin_amdgcn_cvt_pkrtz(a.x, a.y);
        u.h2[1] = __builtin_amdgcn_cvt_pkrtz(a.z, a.w);
        u.h2[2] = __builtin_amdgcn_cvt_pkrtz(b.x, b.y);
        u.h2[3] = __builtin_amdgcn_cvt_pkrtz(b.z, b.w);
        d8[i] = u.h8;
    }
}

// ---------- fused fp16 GEMM + gumbel-sigmoid epilogue ----------
// C[m][n] = sum_k x[m][k]*W[n][k];  out = sigmoid((C + b + g1 - g2)/0.1)
__global__ __launch_bounds__(256, 4) void gumbel_fused(
        const _Float16* __restrict__ xh, const _Float16* __restrict__ wh,
        const float* __restrict__ bias, const float* __restrict__ u1,
        const float* __restrict__ u2, float* __restrict__ out,
        int M, int N, int K) {
    // K-loop: A tile 128x64 fp16 (16 KB) + B tile (16 KB).
    // Epilogue reuses as per-wave transpose buffers (4 x 1280 floats = 20 KB).
    __shared__ _Float16 Smem[2 * BM * BK];
    _Float16* As = Smem;
    _Float16* Bs = Smem + BM * BK;

    const int tid  = threadIdx.x;
    const int lane = tid & 63;
    const int wave = tid >> 6;

    // bid%8 == by%8 for all 8 sharers of an x row-panel -> same XCD L2.
    const int bid = blockIdx.x;
    const int by  = bid & (M / BM - 1);   // M/BM = 128 (pow2)
    const int bx  = bid >> 7;
    const int bm = by * BM;
    const int bn = bx * BN;

    // --- staging: tile = 1024 16B chunks (8 chunks per 64-fp16 row).
    // LDS chunk s <- global (row r = s>>3, chunk col cc = (s&7)^(r&7)).
    // Swizzle on the GLOBAL side; LDS stays lane-ordered
    // (global_load_lds: lds addr = wave-uniform base + lane*16).
    int aoff[4], boff[4], lsoff[4];
#pragma unroll
    for (int rep = 0; rep < 4; rep++) {
        int s = wave * 64 + lane + rep * 256;
        int r = s >> 3;
        int cc = (s & 7) ^ (r & 7);
        aoff[rep] = (bm + r) * K + cc * 8;
        boff[rep] = (bn + r) * K + cc * 8;
        lsoff[rep] = s * 8;   // fp16-element offset
    }

    // --- fragment addressing (16x16x32: A[m=lane&15][k=(lane>>4)*8+j]) ---
    // k-slice s (k = s*32 + quad*8 + 0..7) lives in global chunk s*4+quad,
    // stored at LDS position (s*4+quad)^(r&7): ONE b128 read per fragment.
    const int r16  = lane & 15;
    const int quad = lane >> 4;
    const int wm = (wave & 1) * 64;   // 2x2 wave grid, wave tile 64x64
    const int wn = (wave >> 1) * 64;

    floatx4 acc[4][4] = {};

    int aro[4][2], bro[4][2];
#pragma unroll
    for (int i = 0; i < 4; i++) {
        int ra = wm + i * 16 + r16;
        int rb = wn + i * 16 + r16;
#pragma unroll
        for (int s = 0; s < 2; s++) {
            aro[i][s] = ra * BK + (((s * 4 + quad) ^ (ra & 7)) * 8);
            bro[i][s] = rb * BK + (((s * 4 + quad) ^ (rb & 7)) * 8);
        }
    }

    for (int kb = 0; kb < K; kb += BK) {
#pragma unroll
        for (int rep = 0; rep < 4; rep++) {
            __builtin_amdgcn_global_load_lds(AS1U(xh + aoff[rep] + kb), AS3U(As + lsoff[rep]), 16, 0, 0);
            __builtin_amdgcn_global_load_lds(AS1U(wh + boff[rep] + kb), AS3U(Bs + lsoff[rep]), 16, 0, 0);
        }
        __syncthreads();

#pragma unroll
        for (int s = 0; s < 2; s++) {
            half8 af[4], bf[4];
#pragma unroll
            for (int i = 0; i < 4; i++) {
                af[i] = *(const half8*)(As + aro[i][s]);
                bf[i] = *(const half8*)(Bs + bro[i][s]);
            }
#pragma unroll
            for (int i = 0; i < 4; i++) {
#pragma unroll
                for (int j = 0; j < 4; j++) {
                    acc[i][j] = __builtin_amdgcn_mfma_f32_16x16x32_f16(af[i], bf[j], acc[i][j], 0, 0, 0);
                }
            }
        }
        __syncthreads();
    }

    // --- epilogue (R6-verified): transpose 16x64 acc groups through LDS,
    // then fully-coalesced f4 u1/u2/out accesses. ---
    float* T = ((float*)Smem) + wave * 1280;
    const float inv_t = 10.0f;  // 1/TEMP

#pragma unroll
    for (int i = 0; i < 4; i++) {
        // acc[i][j][r] = C[row = quad*4+r][col = j*16+r16] of this 16x64 group
#pragma unroll
        for (int j = 0; j < 4; j++) {
            int col = j * 16 + r16;
            f4 v = {acc[i][j][0], acc[i][j][1], acc[i][j][2], acc[i][j][3]};
            *(f4*)(T + col * 20 + quad * 4) = v;
        }
        __syncthreads();

#pragma unroll
        for (int rep = 0; rep < 2; rep++) {
#pragma unroll
            for (int rep2 = 0; rep2 < 2; rep2++) {
                int rr = (lane >> 3) + rep * 8;        // row in [0,16)
                int ch = (lane & 7) + rep2 * 8;        // float4 chunk in [0,16)
                int gm = bm + wm + i * 16 + rr;
                int gc = bn + wn + ch * 4;
                f4 l4;
                l4.x = T[(ch * 4 + 0) * 20 + rr];
                l4.y = T[(ch * 4 + 1) * 20 + rr];
                l4.z = T[(ch * 4 + 2) * 20 + rr];
                l4.w = T[(ch * 4 + 3) * 20 + rr];
                f4 bv = *(const f4*)(bias + gc);
                int idx = gm * N + gc;
                f4 v1 = __builtin_nontemporal_load((const f4*)(u1 + idx));
                f4 v2 = __builtin_nontemporal_load((const f4*)(u2 + idx));
                f4 o;
                {
                    float z = (l4.x + bv.x + __logf(__logf(v2.x) / __logf(v1.x))) * inv_t;
                    o.x = 1.0f / (1.0f + __expf(-z));
                }
                {
                    float z = (l4.y + bv.y + __logf(__logf(v2.y) / __logf(v1.y))) * inv_t;
                    o.y = 1.0f / (1.0f + __expf(-z));
                }
                {
                    float z = (l4.z + bv.z + __logf(__logf(v2.z) / __logf(v1.z))) * inv_t;
                    o.z = 1.0f / (1.0f + __expf(-z));
                }
                {
                    float z = (l4.w + bv.w + __logf(__logf(v2.w) / __logf(v1.w))) * inv_t;
                    o.w = 1.0f / (1.0f + __expf(-z));
                }
                __builtin_nontemporal_store(o, (f4*)(out + idx));
            }
        }
        __syncthreads();   // all reads of T done before next i overwrites it
    }
}

extern "C" void kernel_launch(void* const* d_in, const int* in_sizes, int n_in,
                              void* d_out, int out_size, void* d_ws, size_t ws_size,
                              hipStream_t stream) {
    const float* x  = (const float*)d_in[0];
    const float* u1 = (const float*)d_in[1];
    const float* u2 = (const float*)d_in[2];
    const float* W  = (const float*)d_in[3];
    const float* b  = (const float*)d_in[4];
    float* out = (float*)d_out;

    const int N = in_sizes[4];            // 1024
    const int K = in_sizes[3] / N;        // 1024
    const int M = in_sizes[0] / K;        // 16384

    _Float16* xh = (_Float16*)d_ws;
    _Float16* wh = xh + (size_t)M * K;

    const int xblocks = 2048, wblocks = 256;
    cvt_fp32_fp16_2<<<xblocks + wblocks, 256, 0, stream>>>(
        x, xh, (M * K) / 8, W, wh, (N * K) / 8, xblocks);

    dim3 grid((M / BM) * (N / BN));       // 128 * 8 = 1024
    gumbel_fused<<<grid, 256, 0, stream>>>(xh, wh, b, u1, u2, out, M, N, K);
}